// Round 9
// baseline (3992.317 us; speedup 1.0000x reference)
//
#include <hip/hip_runtime.h>

typedef unsigned short u16;
typedef unsigned int u32;
typedef unsigned long long u64;
typedef __attribute__((ext_vector_type(8))) short short8;
typedef __attribute__((ext_vector_type(4))) float floatx4;

#define MFMA16(a,b,c) __builtin_amdgcn_mfma_f32_16x16x32_bf16((a),(b),(c),0,0,0)

#define B_ 512
#define T_ 64
#define D_ 32
#define H_ 512

// bf16 weight workspace layout (u16 elements)
#define OFF_WHR  0
#define OFF_WHZ  262144
#define OFF_WHH  524288
#define OFF_GWHH 786432      // 1536x512
#define OFF_GWIH 1572864     // 1536x1024
#define OFF_PW1T 3145728     // 128x512  (p_w1 transposed)
#define OFF_PW2T 3211264     // 64x128   (p_w2 transposed)
#define WS_ELEMS 3219456
// group buffers (u16 elements)
#define GBUF     3219456
#define GSTRIDE  32768       // per-group u16: hg 8192 + rhg 8192 + xpg 16384
#define HG_OFF   0
#define RHG_OFF  8192
#define XPG_OFF  16384
#define CTR_BYTE 8536064     // (GBUF + 32*GSTRIDE)*2 bytes; 32 ctrs padded to 64B
#define CLAIM_BYTE (CTR_BYTE + 2048)  // 8 u32 per-XCD claim counters

#define LOG2PI_f 1.8378770664093453f
#define LOGOBS_f -4.605170185988091f
#define INV2OBS_f 5000.0f
#define SCAL_OFF 262144

#define AT_ST32(p,v) __hip_atomic_store((p),(v),__ATOMIC_RELAXED,__HIP_MEMORY_SCOPE_AGENT)
#define AT_ST64(p,v) __hip_atomic_store((p),(v),__ATOMIC_RELAXED,__HIP_MEMORY_SCOPE_AGENT)
#define AT_LD64(p)   __hip_atomic_load((p),__ATOMIC_RELAXED,__HIP_MEMORY_SCOPE_AGENT)

__device__ __forceinline__ u16 f2bf(float f) {
  union { float f; unsigned u; } v; v.f = f;
  unsigned r = v.u + 0x7FFFu + ((v.u >> 16) & 1u);
  return (u16)(r >> 16);
}
__device__ __forceinline__ u32 pack2(float a, float b) {
  return (u32)f2bf(a) | ((u32)f2bf(b) << 16);
}
__device__ __forceinline__ float sigm(float x) { return 1.f / (1.f + expf(-x)); }

// A-fragment read from swizzled LDS tile
__device__ __forceinline__ short8 ldA(const u16* buf, int rowB, int row, int kE) {
  int byte = row * rowB + (((kE << 1)) ^ ((row & 7) << 4));
  return *(const short8*)((const char*)buf + byte);
}

__global__ void convw(const float* __restrict__ whr, const float* __restrict__ whz,
                      const float* __restrict__ whh, const float* __restrict__ gwhh,
                      const float* __restrict__ gwih, const float* __restrict__ pw1,
                      const float* __restrict__ pw2, u16* __restrict__ ws) {
  int i = blockIdx.x * 256 + threadIdx.x;
  if (i >= WS_ELEMS) return;
  float v;
  if (i < OFF_WHZ) v = whr[i];
  else if (i < OFF_GWHH) {
    if (i < OFF_WHH) v = whz[i - OFF_WHZ];
    else v = whh[i - OFF_WHH];
  } else if (i < OFF_GWIH) v = gwhh[i - OFF_GWHH];
  else if (i < OFF_PW1T) v = gwih[i - OFF_GWIH];
  else if (i < OFF_PW2T) { int l = i - OFF_PW1T; int j = l >> 9, k = l & 511; v = pw1[k * 128 + j]; }
  else { int l = i - OFF_PW2T; int j = l >> 7, k = l & 127; v = pw2[k * 64 + j]; }
  ws[i] = f2bf(v);
}

// Fence-free group barrier: data is exchanged only via agent-scope atomics
// (coherent at L3), so no L2 writeback/invalidate is ever needed.
__device__ __forceinline__ void group_barrier(u32* ctr, unsigned* ep) {
  asm volatile("s_waitcnt vmcnt(0)" ::: "memory");  // per-wave: publishes complete
  __syncthreads();
  unsigned target = 8u * (++(*ep));
  if (threadIdx.x == 0) {
    __hip_atomic_fetch_add(ctr, 1u, __ATOMIC_RELAXED, __HIP_MEMORY_SCOPE_AGENT);
    while (__hip_atomic_load(ctr, __ATOMIC_RELAXED, __HIP_MEMORY_SCOPE_AGENT) < target)
      __builtin_amdgcn_s_sleep(1);
  }
  __syncthreads();
}

// 256 WGs; role (group g, slice s) claimed at runtime from HW_REG_XCC_ID so
// that slice s's weights are L2-resident on XCD s REGARDLESS of dispatch
// mapping. 1 WG/CU (LDS>80KB) + grid==CU count => exactly 32 WGs/XCD.
__global__ __launch_bounds__(512, 2)
void nnfo_main(const float* __restrict__ times, const float* __restrict__ Xg,
               const float* __restrict__ Mgl, const float* __restrict__ cov,
               const float* __restrict__ cov_w1, const float* __restrict__ cov_b1,
               const float* __restrict__ cov_w2, const float* __restrict__ cov_b2,
               const float* __restrict__ p_b1, const float* __restrict__ p_b2,
               const float* __restrict__ wprep, const float* __restrict__ bprep,
               const float* __restrict__ gru_bih, const float* __restrict__ gru_bhh,
               const int* __restrict__ num_obs, u16* __restrict__ ws,
               float* __restrict__ out) {
  __shared__ u16 bufA[8192];       // 16KB: h / rh A-tiles (swizzled, rowB=1024)
  __shared__ u16 xpL[16384];       // 32KB: xp A-tile (swizzled, rowB=2048)
  __shared__ float accbuf[8192];   // 32KB: MFMA partials
  __shared__ u16 hid1A[2048];      // 4KB (swizzled, rowB=256)
  __shared__ float pbuf[1024];     // 4KB  [16][64]
  __shared__ float h_own[1024];    // 4KB  [16][64] f32 owned h cols
  __shared__ float zbuf[1024];     // 4KB
  __shared__ float invden[T_];
  __shared__ float mr16[16], df16[16], lt16[16];
  __shared__ int nobs16[16];
  __shared__ float redbuf[24];
  __shared__ int gs_sh[2];

  const int tid = threadIdx.x;
  const int wv = tid >> 6;
  const int lane = tid & 63;
  const int colc = lane & 15;
  const int khalf = lane >> 4;
  const int rowc = khalf << 2;

  // ---- role claim: s = physical XCD, g = claim order within XCD (0..31)
  if (tid == 0) {
    unsigned xcc;
    asm volatile("s_getreg_b32 %0, hwreg(HW_REG_XCC_ID)" : "=s"(xcc));
    xcc &= 7u;
    u32* claim = (u32*)((char*)ws + CLAIM_BYTE);
    unsigned c = __hip_atomic_fetch_add(&claim[xcc], 1u, __ATOMIC_RELAXED,
                                        __HIP_MEMORY_SCOPE_AGENT);
    gs_sh[0] = (int)(c & 31u);
    gs_sh[1] = (int)xcc;
  }
  __syncthreads();
  const int g = gs_sh[0];        // row-group
  const int s = gs_sh[1];        // col-slice == this WG's XCD
  const int b0 = g << 4;

  const u16* Whr  = ws + OFF_WHR;
  const u16* Whz  = ws + OFF_WHZ;
  const u16* Whh  = ws + OFF_WHH;
  const u16* Gwhh = ws + OFF_GWHH;
  const u16* Gwih = ws + OFF_GWIH;
  const u16* Pw1T = ws + OFF_PW1T;
  const u16* Pw2T = ws + OFF_PW2T;
  u16* hg  = ws + GBUF + g * GSTRIDE + HG_OFF;
  u16* rhg = ws + GBUF + g * GSTRIDE + RHG_OFF;
  u16* xpg = ws + GBUF + g * GSTRIDE + XPG_OFF;
  u32* ctr = (u32*)((char*)ws + CTR_BYTE) + g * 16;
  unsigned ep = 0;

  // ---- init: invden, per-row state
  for (int t = tid; t < T_; t += 512) {
    int cnt = 0;
    for (int b = 0; b < B_; ++b) cnt += (num_obs[b] > t) ? 1 : 0;
    invden[t] = 1.0f / fmaxf((float)cnt * (float)D_, 1.0f);
  }
  if (tid < 16) { nobs16[tid] = num_obs[b0 + tid]; lt16[tid] = 0.f; }
  // ---- h0 (each WG computes full h0 for its 16 rows; scalar, one-time)
  for (int i = tid; i < 16 * 64; i += 512) {
    int m = i >> 6, k = i & 63;
    pbuf[i] = cov[(b0 + m) * 64 + k];
  }
  __syncthreads();
  for (int i = tid; i < 16 * 128; i += 512) {
    int m = i >> 7, j = i & 127;
    float sacc = cov_b1[j];
    for (int k = 0; k < 64; ++k) sacc += pbuf[m * 64 + k] * cov_w1[k * 128 + j];
    accbuf[i] = fmaxf(sacc, 0.f);
  }
  __syncthreads();
  {
    int row = tid >> 5, colb = (tid & 31) << 4;
    for (int c = 0; c < 16; ++c) {
      int col = colb + c;
      float sacc = cov_b2[col];
      for (int k = 0; k < 128; ++k) sacc += accbuf[row * 128 + k] * cov_w2[k * 512 + col];
      float v = tanhf(sacc);
      int byte = (row << 10) | (((col << 1)) ^ ((row & 7) << 4));
      *(u16*)((char*)bufA + byte) = f2bf(v);
      if ((col >> 6) == s) h_own[row * 64 + (col & 63)] = v;
    }
  }
  float l1a = 0.f, l2a = 0.f, nlla = 0.f;
  float Xc_s = 0.f, Mc_s = 0.f;
  __syncthreads();

  const int row_l = tid >> 5;            // L-phase mapping
  const int dloc  = (tid >> 3) & 3;
  const int pq    = tid & 7;
  const int d_l   = (s << 2) + dloc;
  const int cp    = tid & 31;            // pair-col index for publish phases

  for (int t = 0; t < T_; ++t) {
    // S0
    if (tid < 16) {
      float tcv = times[(b0 + tid) * T_ + t];
      float mm = (t < nobs16[tid]) ? 1.f : 0.f;
      df16[tid] = (tcv - lt16[tid]) * mm;
      mr16[tid] = mm;
      lt16[tid] = (mm > 0.f) ? tcv : lt16[tid];
    }
    // O1 jobs: r (waves 0-3), z (waves 4-7), col-tile = wv&3
    {
      int mat = wv >> 2, jt = wv & 3;
      int colg = (s << 6) + (jt << 4) + colc;
      const u16* W = (mat ? Whz : Whr) + colg * 512;
      floatx4 acc = (floatx4){0.f,0.f,0.f,0.f};
      #pragma unroll
      for (int kc = 0; kc < 16; ++kc) {
        int kE = (kc << 5) + (khalf << 3);
        acc = MFMA16(ldA(bufA, 1024, colc, kE), *(const short8*)(W + kE), acc);
      }
      #pragma unroll
      for (int i = 0; i < 4; ++i)
        accbuf[mat * 1024 + (rowc + i) * 64 + (jt << 4) + colc] = acc[i];
    }
    __syncthreads();
    // O1 elementwise: r,z ; publish rh (packed u32 agent atomics)
    {
      int p0 = (row_l << 6) + (cp << 1);
      float rv0 = sigm(accbuf[p0]);
      float rv1 = sigm(accbuf[p0 + 1]);
      zbuf[p0]     = sigm(accbuf[1024 + p0]);
      zbuf[p0 + 1] = sigm(accbuf[1024 + p0 + 1]);
      AT_ST32((u32*)(rhg + (row_l << 9) + (s << 6) + (cp << 1)),
              pack2(rv0 * h_own[p0], rv1 * h_own[p0 + 1]));
    }
    group_barrier(ctr, &ep);                       // B1
    // stage rh -> bufA (u64 agent atomic loads)
    {
      u64 tmp[4];
      #pragma unroll
      for (int i = 0; i < 4; ++i) tmp[i] = AT_LD64((const u64*)rhg + tid + 512 * i);
      #pragma unroll
      for (int i = 0; i < 4; ++i) {
        int e = (tid + 512 * i) << 2;
        int row = e >> 9, col = e & 511;
        *(u64*)((char*)bufA + (row << 10) + (((col << 1)) ^ ((row & 7) << 4))) = tmp[i];
      }
    }
    __syncthreads();
    // O2 jobs: u, tiles x K-halves
    {
      int jt = wv & 3, kh = wv >> 2;
      int colg = (s << 6) + (jt << 4) + colc;
      const u16* W = Whh + colg * 512;
      floatx4 acc = (floatx4){0.f,0.f,0.f,0.f};
      #pragma unroll
      for (int kc = kh * 8; kc < kh * 8 + 8; ++kc) {
        int kE = (kc << 5) + (khalf << 3);
        acc = MFMA16(ldA(bufA, 1024, colc, kE), *(const short8*)(W + kE), acc);
      }
      #pragma unroll
      for (int i = 0; i < 4; ++i)
        accbuf[kh * 1024 + (rowc + i) * 64 + (jt << 4) + colc] = acc[i];
    }
    __syncthreads();
    // O2 elementwise: h' ; publish h'
    {
      int p0 = (row_l << 6) + (cp << 1);
      float u0 = tanhf(accbuf[p0] + accbuf[1024 + p0]);
      float u1 = tanhf(accbuf[p0 + 1] + accbuf[1024 + p0 + 1]);
      float h0v = h_own[p0], h1v = h_own[p0 + 1];
      float dd = df16[row_l];
      float hn0 = h0v + (1.f - zbuf[p0]) * (u0 - h0v) * dd;
      float hn1 = h1v + (1.f - zbuf[p0 + 1]) * (u1 - h1v) * dd;
      h_own[p0] = hn0; h_own[p0 + 1] = hn1;
      AT_ST32((u32*)(hg + (row_l << 9) + (s << 6) + (cp << 1)), pack2(hn0, hn1));
    }
    group_barrier(ctr, &ep);                       // B2
    // stage h' -> bufA
    {
      u64 tmp[4];
      #pragma unroll
      for (int i = 0; i < 4; ++i) tmp[i] = AT_LD64((const u64*)hg + tid + 512 * i);
      #pragma unroll
      for (int i = 0; i < 4; ++i) {
        int e = (tid + 512 * i) << 2;
        int row = e >> 9, col = e & 511;
        *(u64*)((char*)bufA + (row << 10) + (((col << 1)) ^ ((row & 7) << 4))) = tmp[i];
      }
    }
    __syncthreads();
    // P1: full hid1 (8 col-tiles over 8 waves)
    {
      int colg = (wv << 4) + colc;
      const u16* W = Pw1T + colg * 512;
      floatx4 acc = (floatx4){0.f,0.f,0.f,0.f};
      #pragma unroll
      for (int kc = 0; kc < 16; ++kc) {
        int kE = (kc << 5) + (khalf << 3);
        acc = MFMA16(ldA(bufA, 1024, colc, kE), *(const short8*)(W + kE), acc);
      }
      float bias = p_b1[colg];
      #pragma unroll
      for (int i = 0; i < 4; ++i) {
        int row = rowc + i;
        float v = fmaxf(acc[i] + bias, 0.f);
        *(u16*)((char*)hid1A + ((row << 8) | (((colg << 1)) ^ ((row & 7) << 4)))) = f2bf(v);
      }
    }
    __syncthreads();
    // P2: full p (waves 0-3)
    if (wv < 4) {
      int colg = (wv << 4) + colc;
      const u16* W = Pw2T + colg * 128;
      floatx4 acc = (floatx4){0.f,0.f,0.f,0.f};
      #pragma unroll
      for (int kc = 0; kc < 4; ++kc) {
        int kE = (kc << 5) + (khalf << 3);
        acc = MFMA16(ldA(hid1A, 256, colc, kE), *(const short8*)(W + kE), acc);
      }
      float bias = p_b2[colg];
      #pragma unroll
      for (int i = 0; i < 4; ++i) pbuf[(rowc + i) * 64 + colg] = acc[i] + bias;
    }
    __syncthreads();
    // L: losses (owned d) + xp slice publish (u64 atomic)
    {
      float mean = pbuf[row_l * 64 + d_l];
      float logvar = pbuf[row_l * 64 + 32 + d_l];
      size_t xoff = ((size_t)(b0 + row_l) * T_ + t) * D_ + d_l;
      Xc_s = Xg[xoff];
      Mc_s = Mgl[xoff];
      float mm = mr16[row_l];
      float sg = expf(0.5f * logvar);
      float err = (Xc_s - mean) / sg;
      if (pq == 0) {
        float lv = 0.5f * (err * err + logvar + LOG2PI_f) * Mc_s * mm;
        l1a += lv;
        nlla += lv * invden[t];
      }
      const float* wp = wprep + d_l * 128;
      const float* bp = bprep + d_l * 32;
      float xv[4];
      #pragma unroll
      for (int k = 0; k < 4; ++k) {
        int pi = (pq << 2) + k;
        float v = bp[pi] + Xc_s * wp[pi] + mean * wp[32 + pi] + logvar * wp[64 + pi] + err * wp[96 + pi];
        xv[k] = fmaxf(v, 0.f) * Mc_s;
      }
      u64 packed = (u64)pack2(xv[0], xv[1]) | ((u64)pack2(xv[2], xv[3]) << 32);
      AT_ST64((u64*)(xpg + (row_l << 10) + (s << 7) + (dloc << 5) + (pq << 2)), packed);
    }
    group_barrier(ctr, &ep);                       // B3
    // stage xp -> xpL
    {
      u64 tmp[8];
      #pragma unroll
      for (int i = 0; i < 8; ++i) tmp[i] = AT_LD64((const u64*)xpg + tid + 512 * i);
      #pragma unroll
      for (int i = 0; i < 8; ++i) {
        int e = (tid + 512 * i) << 2;
        int row = e >> 10, col = e & 1023;
        *(u64*)((char*)xpL + (row << 11) + (((col << 1)) ^ ((row & 7) << 4))) = tmp[i];
      }
    }
    __syncthreads();
    // G jobs: tiles x K-halves; 4 gate-accs per wave
    {
      int jt = wv & 3, kh = wv >> 2;
      int colg = (s << 6) + (jt << 4) + colc;
      const u16* bw = Gwhh + colg * 512;
      const u16* bi = Gwih + colg * 1024;
      floatx4 ar = (floatx4){0.f,0.f,0.f,0.f}, az = ar, an = ar, ah = ar;
      #pragma unroll
      for (int kc = kh * 8; kc < kh * 8 + 8; ++kc) {
        int kE = (kc << 5) + (khalf << 3);
        short8 a = ldA(bufA, 1024, colc, kE);
        ar = MFMA16(a, *(const short8*)(bw + kE), ar);
        az = MFMA16(a, *(const short8*)(bw + 262144 + kE), az);
        ah = MFMA16(a, *(const short8*)(bw + 524288 + kE), ah);
      }
      #pragma unroll
      for (int kc = kh * 16; kc < kh * 16 + 16; ++kc) {
        int kE = (kc << 5) + (khalf << 3);
        short8 a = ldA(xpL, 2048, colc, kE);
        ar = MFMA16(a, *(const short8*)(bi + kE), ar);
        az = MFMA16(a, *(const short8*)(bi + 524288 + kE), az);
        an = MFMA16(a, *(const short8*)(bi + 1048576 + kE), an);
      }
      #pragma unroll
      for (int i = 0; i < 4; ++i) {
        int idx = (rowc + i) * 64 + (jt << 4) + colc;
        accbuf[(0 + kh) * 1024 + idx] = ar[i];
        accbuf[(2 + kh) * 1024 + idx] = az[i];
        accbuf[(4 + kh) * 1024 + idx] = an[i];
        accbuf[(6 + kh) * 1024 + idx] = ah[i];
      }
    }
    __syncthreads();
    // G elementwise: gates, h'' ; publish h''
    {
      int p0 = (row_l << 6) + (cp << 1);
      float hn[2];
      float mm = mr16[row_l];
      #pragma unroll
      for (int q = 0; q < 2; ++q) {
        int p = p0 + q;
        int j = (s << 6) + (cp << 1) + q;
        float Arr = accbuf[p] + accbuf[1024 + p];
        float Azz = accbuf[2048 + p] + accbuf[3072 + p];
        float Ann = accbuf[4096 + p] + accbuf[5120 + p];
        float Ahh = accbuf[6144 + p] + accbuf[7168 + p];
        float rg = sigm(Arr + gru_bih[j] + gru_bhh[j]);
        float zg = sigm(Azz + gru_bih[512 + j] + gru_bhh[512 + j]);
        float ng = tanhf(Ann + gru_bih[1024 + j] + rg * (Ahh + gru_bhh[1024 + j]));
        float h = h_own[p];
        float hv = (1.f - zg) * ng + zg * h;
        hv = (mm > 0.f) ? hv : h;
        h_own[p] = hv;
        hn[q] = hv;
      }
      AT_ST32((u32*)(hg + (row_l << 9) + (s << 6) + (cp << 1)), pack2(hn[0], hn[1]));
    }
    group_barrier(ctr, &ep);                       // B4
    // stage h'' -> bufA
    {
      u64 tmp[4];
      #pragma unroll
      for (int i = 0; i < 4; ++i) tmp[i] = AT_LD64((const u64*)hg + tid + 512 * i);
      #pragma unroll
      for (int i = 0; i < 4; ++i) {
        int e = (tid + 512 * i) << 2;
        int row = e >> 9, col = e & 511;
        *(u64*)((char*)bufA + (row << 10) + (((col << 1)) ^ ((row & 7) << 4))) = tmp[i];
      }
    }
    __syncthreads();
    // P1': full hid1(h'')
    {
      int colg = (wv << 4) + colc;
      const u16* W = Pw1T + colg * 512;
      floatx4 acc = (floatx4){0.f,0.f,0.f,0.f};
      #pragma unroll
      for (int kc = 0; kc < 16; ++kc) {
        int kE = (kc << 5) + (khalf << 3);
        acc = MFMA16(ldA(bufA, 1024, colc, kE), *(const short8*)(W + kE), acc);
      }
      float bias = p_b1[colg];
      #pragma unroll
      for (int i = 0; i < 4; ++i) {
        int row = rowc + i;
        float v = fmaxf(acc[i] + bias, 0.f);
        *(u16*)((char*)hid1A + ((row << 8) | (((colg << 1)) ^ ((row & 7) << 4)))) = f2bf(v);
      }
    }
    __syncthreads();
    // P2': p2
    if (wv < 4) {
      int colg = (wv << 4) + colc;
      const u16* W = Pw2T + colg * 128;
      floatx4 acc = (floatx4){0.f,0.f,0.f,0.f};
      #pragma unroll
      for (int kc = 0; kc < 4; ++kc) {
        int kE = (kc << 5) + (khalf << 3);
        acc = MFMA16(ldA(hid1A, 256, colc, kE), *(const short8*)(W + kE), acc);
      }
      float bias = p_b2[colg];
      #pragma unroll
      for (int i = 0; i < 4; ++i) pbuf[(rowc + i) * 64 + colg] = acc[i] + bias;
    }
    __syncthreads();
    // L': kl (owned d)
    if (pq == 0) {
      float mean2 = pbuf[row_l * 64 + d_l];
      float logvar2 = pbuf[row_l * 64 + 32 + d_l];
      float s2 = expf(logvar2);
      float dm = mean2 - Xc_s;
      float kl = LOGOBS_f - 0.5f * logvar2 + (s2 + dm * dm) * INV2OBS_f - 0.5f;
      l2a += kl * Mc_s * mr16[row_l];
    }
    __syncthreads();   // protect mr16/df16/pbuf/hid1A for next iteration
  }

  // final h out (owned slice)
  for (int pos = tid; pos < 1024; pos += 512) {
    int row = pos >> 6, cl = pos & 63;
    out[(size_t)(b0 + row) * H_ + (s << 6) + cl] = h_own[pos];
  }
  // scalar reductions
  #pragma unroll
  for (int off = 32; off > 0; off >>= 1) {
    l1a += __shfl_down(l1a, off, 64);
    l2a += __shfl_down(l2a, off, 64);
    nlla += __shfl_down(nlla, off, 64);
  }
  if (lane == 0) { redbuf[wv] = l1a; redbuf[8 + wv] = l2a; redbuf[16 + wv] = nlla; }
  __syncthreads();
  if (tid == 0) {
    float L1 = 0.f, L2 = 0.f, NL = 0.f;
    for (int w = 0; w < 8; ++w) { L1 += redbuf[w]; L2 += redbuf[8 + w]; NL += redbuf[16 + w]; }
    atomicAdd(out + SCAL_OFF + 0, L1 + 0.1f * L2);
    atomicAdd(out + SCAL_OFF + 1, NL * (1.f / 64.f));
    atomicAdd(out + SCAL_OFF + 2, L1);
    atomicAdd(out + SCAL_OFF + 3, L2);
  }
}

extern "C" void kernel_launch(void* const* d_in, const int* in_sizes, int n_in,
                              void* d_out, int out_size, void* d_ws, size_t ws_size,
                              hipStream_t stream) {
  const float* times  = (const float*)d_in[0];
  const float* X      = (const float*)d_in[1];
  const float* M      = (const float*)d_in[2];
  const float* cov    = (const float*)d_in[3];
  const float* cov_w1 = (const float*)d_in[5];
  const float* cov_b1 = (const float*)d_in[6];
  const float* cov_w2 = (const float*)d_in[7];
  const float* cov_b2 = (const float*)d_in[8];
  const float* p_w1   = (const float*)d_in[9];
  const float* p_b1   = (const float*)d_in[10];
  const float* p_w2   = (const float*)d_in[11];
  const float* p_b2   = (const float*)d_in[12];
  const float* ode_whr = (const float*)d_in[13];
  const float* ode_whz = (const float*)d_in[14];
  const float* ode_whh = (const float*)d_in[15];
  const float* wprep  = (const float*)d_in[16];
  const float* bprep  = (const float*)d_in[17];
  const float* gru_wih = (const float*)d_in[18];
  const float* gru_whh = (const float*)d_in[19];
  const float* gru_bih = (const float*)d_in[20];
  const float* gru_bhh = (const float*)d_in[21];
  const int* num_obs  = (const int*)d_in[22];
  float* out = (float*)d_out;
  u16* ws = (u16*)d_ws;

  hipMemsetAsync(out + SCAL_OFF, 0, 4 * sizeof(float), stream);
  // barrier counters (32x64B) + per-XCD claim counters (64B)
  hipMemsetAsync((char*)d_ws + CTR_BYTE, 0, 2048 + 64, stream);
  convw<<<dim3((WS_ELEMS + 255) / 256), dim3(256), 0, stream>>>(
      ode_whr, ode_whz, ode_whh, gru_whh, gru_wih, p_w1, p_w2, ws);

  void* args[] = { (void*)&times, (void*)&X, (void*)&M, (void*)&cov,
                   (void*)&cov_w1, (void*)&cov_b1, (void*)&cov_w2, (void*)&cov_b2,
                   (void*)&p_b1, (void*)&p_b2, (void*)&wprep, (void*)&bprep,
                   (void*)&gru_bih, (void*)&gru_bhh, (void*)&num_obs, (void*)&ws,
                   (void*)&out };
  hipError_t e = hipLaunchCooperativeKernel((const void*)nnfo_main, dim3(256), dim3(512),
                                            args, 0, stream);
  if (e != hipSuccess) {
    // Fallback: plain launch. LDS (97KB) forces 1 WG/CU; grid==CU count -> co-resident.
    nnfo_main<<<dim3(256), dim3(512), 0, stream>>>(
        times, X, M, cov, cov_w1, cov_b1, cov_w2, cov_b2,
        p_b1, p_b2, wprep, bprep, gru_bih, gru_bhh, num_obs, ws, out);
  }
}

// Round 12
// 3688.860 us; speedup vs baseline: 1.0823x; 1.0823x over previous
//
#include <hip/hip_runtime.h>

typedef unsigned short u16;
typedef unsigned int u32;
typedef unsigned long long u64;
typedef __attribute__((ext_vector_type(8))) short short8;
typedef __attribute__((ext_vector_type(4))) float floatx4;
typedef __attribute__((ext_vector_type(4))) unsigned int u32x4;

#define MFMA16(a,b,c) __builtin_amdgcn_mfma_f32_16x16x32_bf16((a),(b),(c),0,0,0)

#define B_ 512
#define T_ 64
#define D_ 32
#define H_ 512

// bf16 weight workspace layout (u16 elements)
#define OFF_WHR  0
#define OFF_WHZ  262144
#define OFF_WHH  524288
#define OFF_GWHH 786432      // 1536x512
#define OFF_GWIH 1572864     // 1536x1024
#define OFF_PW1T 3145728     // 128x512  (p_w1 transposed)
#define OFF_PW2T 3211264     // 64x128   (p_w2 transposed)
#define WS_ELEMS 3219456
// group buffers (u16 elements)
#define GBUF     3219456
#define GSTRIDE  32768       // per-group u16: hg 8192 + rhg 8192 + xpg 16384
#define HG_OFF   0
#define RHG_OFF  8192
#define XPG_OFF  16384
#define CTR_BYTE 8536064     // 32 ctrs padded to 64B
#define CLAIM_BYTE (CTR_BYTE + 2048)  // 8 u32 per-XCD claim counters

#define LOG2PI_f 1.8378770664093453f
#define LOGOBS_f -4.605170185988091f
#define INV2OBS_f 5000.0f
#define SCAL_OFF 262144

__device__ __forceinline__ u16 f2bf(float f) {
  union { float f; unsigned u; } v; v.f = f;
  unsigned r = v.u + 0x7FFFu + ((v.u >> 16) & 1u);
  return (u16)(r >> 16);
}
__device__ __forceinline__ u32 pack2(float a, float b) {
  return (u32)f2bf(a) | ((u32)f2bf(b) << 16);
}
__device__ __forceinline__ float sigm(float x) { return 1.f / (1.f + expf(-x)); }

// Coherent (L1/L2-bypassing) COALESCED exchange ops — same sc0|sc1 bits the
// compiler emits for relaxed agent atomics, but as normal vector mem ops so
// a wave's 64 lanes coalesce into line-granule L3 requests and pipeline.
__device__ __forceinline__ u32x4 ldg_cc16(const void* p) {
  u32x4 r;
  asm volatile("global_load_dwordx4 %0, %1, off sc0 sc1"
               : "=v"(r) : "v"(p) : "memory");
  return r;
}
__device__ __forceinline__ void stg_cc4(void* p, u32 v) {
  asm volatile("global_store_dword %0, %1, off sc0 sc1"
               :: "v"(p), "v"(v) : "memory");
}
__device__ __forceinline__ void stg_cc8(void* p, u64 v) {
  asm volatile("global_store_dwordx2 %0, %1, off sc0 sc1"
               :: "v"(p), "v"(v) : "memory");
}

// A-fragment read from swizzled LDS tile
__device__ __forceinline__ short8 ldA(const u16* buf, int rowB, int row, int kE) {
  int byte = row * rowB + (((kE << 1)) ^ ((row & 7) << 4));
  return *(const short8*)((const char*)buf + byte);
}

__global__ void convw(const float* __restrict__ whr, const float* __restrict__ whz,
                      const float* __restrict__ whh, const float* __restrict__ gwhh,
                      const float* __restrict__ gwih, const float* __restrict__ pw1,
                      const float* __restrict__ pw2, u16* __restrict__ ws) {
  int i = blockIdx.x * 256 + threadIdx.x;
  if (i >= WS_ELEMS) return;
  float v;
  if (i < OFF_WHZ) v = whr[i];
  else if (i < OFF_GWHH) {
    if (i < OFF_WHH) v = whz[i - OFF_WHZ];
    else v = whh[i - OFF_WHH];
  } else if (i < OFF_GWIH) v = gwhh[i - OFF_GWHH];
  else if (i < OFF_PW1T) v = gwih[i - OFF_GWIH];
  else if (i < OFF_PW2T) { int l = i - OFF_PW1T; int j = l >> 9, k = l & 511; v = pw1[k * 128 + j]; }
  else { int l = i - OFF_PW2T; int j = l >> 7, k = l & 127; v = pw2[k * 64 + j]; }
  ws[i] = f2bf(v);
}

// split barrier: arrive (drain + count) / wait (poll) — lets real work hide
// the rendezvous between the two halves.
__device__ __forceinline__ void gb_arrive(u32* ctr) {
  asm volatile("s_waitcnt vmcnt(0)" ::: "memory");  // publishes at L3
  __syncthreads();
  if (threadIdx.x == 0)
    __hip_atomic_fetch_add(ctr, 1u, __ATOMIC_RELAXED, __HIP_MEMORY_SCOPE_AGENT);
}
__device__ __forceinline__ void gb_wait(u32* ctr, unsigned* ep) {
  unsigned target = 8u * (++(*ep));
  if (threadIdx.x == 0) {
    while (__hip_atomic_load(ctr, __ATOMIC_RELAXED, __HIP_MEMORY_SCOPE_AGENT) < target)
      __builtin_amdgcn_s_sleep(1);
  }
  __syncthreads();
}

// 256 WGs; role (g,s) claimed from HW_REG_XCC_ID: slice s's weights stay
// L2-resident on XCD s regardless of dispatch mapping.
__global__ __launch_bounds__(512, 2)
void nnfo_main(const float* __restrict__ times, const float* __restrict__ Xg,
               const float* __restrict__ Mgl, const float* __restrict__ cov,
               const float* __restrict__ cov_w1, const float* __restrict__ cov_b1,
               const float* __restrict__ cov_w2, const float* __restrict__ cov_b2,
               const float* __restrict__ p_b1, const float* __restrict__ p_b2,
               const float* __restrict__ wprep, const float* __restrict__ bprep,
               const float* __restrict__ gru_bih, const float* __restrict__ gru_bhh,
               const int* __restrict__ num_obs, u16* __restrict__ ws,
               float* __restrict__ out) {
  __shared__ u16 bufA[8192];       // 16KB: h / rh A-tiles (swizzled, rowB=1024)
  __shared__ u16 xpL[16384];       // 32KB: xp A-tile (swizzled, rowB=2048)
  __shared__ float accbuf[8192];   // 32KB: MFMA partials
  __shared__ u16 hid1A[2048];      // 4KB (swizzled, rowB=256)
  __shared__ float pbuf[1024];     // 4KB  [16][64]
  __shared__ float h_own[1024];    // 4KB  [16][64] f32 owned h cols
  __shared__ float zbuf[1024];     // 4KB
  __shared__ float invden[T_];
  __shared__ float mr16[16], df16[16], lt16[16];
  __shared__ int nobs16[16];
  __shared__ float redbuf[24];
  __shared__ int gs_sh[2];

  const int tid = threadIdx.x;
  const int wv = tid >> 6;
  const int lane = tid & 63;
  const int colc = lane & 15;
  const int khalf = lane >> 4;
  const int rowc = khalf << 2;

  // ---- role claim: s = physical XCD, g = claim order within XCD (0..31)
  if (tid == 0) {
    unsigned xcc;
    asm volatile("s_getreg_b32 %0, hwreg(HW_REG_XCC_ID)" : "=s"(xcc));
    xcc &= 7u;
    u32* claim = (u32*)((char*)ws + CLAIM_BYTE);
    unsigned c = __hip_atomic_fetch_add(&claim[xcc], 1u, __ATOMIC_RELAXED,
                                        __HIP_MEMORY_SCOPE_AGENT);
    gs_sh[0] = (int)(c & 31u);
    gs_sh[1] = (int)xcc;
  }
  __syncthreads();
  const int g = gs_sh[0];
  const int s = gs_sh[1];
  const int b0 = g << 4;

  const u16* Whr  = ws + OFF_WHR;
  const u16* Whz  = ws + OFF_WHZ;
  const u16* Whh  = ws + OFF_WHH;
  const u16* Gwhh = ws + OFF_GWHH;
  const u16* Gwih = ws + OFF_GWIH;
  const u16* Pw1T = ws + OFF_PW1T;
  const u16* Pw2T = ws + OFF_PW2T;
  u16* hg  = ws + GBUF + g * GSTRIDE + HG_OFF;
  u16* rhg = ws + GBUF + g * GSTRIDE + RHG_OFF;
  u16* xpg = ws + GBUF + g * GSTRIDE + XPG_OFF;
  u32* ctr = (u32*)((char*)ws + CTR_BYTE) + g * 16;
  unsigned ep = 0;

  // ---- init
  for (int t = tid; t < T_; t += 512) {
    int cnt = 0;
    for (int b = 0; b < B_; ++b) cnt += (num_obs[b] > t) ? 1 : 0;
    invden[t] = 1.0f / fmaxf((float)cnt * (float)D_, 1.0f);
  }
  if (tid < 16) { nobs16[tid] = num_obs[b0 + tid]; lt16[tid] = 0.f; }
  for (int i = tid; i < 16 * 64; i += 512) {
    int m = i >> 6, k = i & 63;
    pbuf[i] = cov[(b0 + m) * 64 + k];
  }
  __syncthreads();
  for (int i = tid; i < 16 * 128; i += 512) {
    int m = i >> 7, j = i & 127;
    float sacc = cov_b1[j];
    for (int k = 0; k < 64; ++k) sacc += pbuf[m * 64 + k] * cov_w1[k * 128 + j];
    accbuf[i] = fmaxf(sacc, 0.f);
  }
  __syncthreads();
  {
    int row = tid >> 5, colb = (tid & 31) << 4;
    for (int c = 0; c < 16; ++c) {
      int col = colb + c;
      float sacc = cov_b2[col];
      for (int k = 0; k < 128; ++k) sacc += accbuf[row * 128 + k] * cov_w2[k * 512 + col];
      float v = tanhf(sacc);
      int byte = (row << 10) | (((col << 1)) ^ ((row & 7) << 4));
      *(u16*)((char*)bufA + byte) = f2bf(v);
      if ((col >> 6) == s) h_own[row * 64 + (col & 63)] = v;
    }
  }
  float l1a = 0.f, l2a = 0.f, nlla = 0.f;
  float Xc_s = 0.f, Mc_s = 0.f;
  __syncthreads();

  const int row_l = tid >> 5;
  const int dloc  = (tid >> 3) & 3;
  const int pq    = tid & 7;
  const int d_l   = (s << 2) + dloc;
  const int cp    = tid & 31;
  const int jtG = wv & 3, khG = wv >> 2;

  for (int t = 0; t < T_; ++t) {
    // S0
    if (tid < 16) {
      float tcv = times[(b0 + tid) * T_ + t];
      float mm = (t < nobs16[tid]) ? 1.f : 0.f;
      df16[tid] = (tcv - lt16[tid]) * mm;
      mr16[tid] = mm;
      lt16[tid] = (mm > 0.f) ? tcv : lt16[tid];
    }
    // O1 jobs: r (waves 0-3), z (waves 4-7)
    {
      int mat = wv >> 2, jt = wv & 3;
      int colg = (s << 6) + (jt << 4) + colc;
      const u16* W = (mat ? Whz : Whr) + colg * 512;
      floatx4 acc = (floatx4){0.f,0.f,0.f,0.f};
      #pragma unroll
      for (int kc = 0; kc < 16; ++kc) {
        int kE = (kc << 5) + (khalf << 3);
        acc = MFMA16(ldA(bufA, 1024, colc, kE), *(const short8*)(W + kE), acc);
      }
      #pragma unroll
      for (int i = 0; i < 4; ++i)
        accbuf[mat * 1024 + (rowc + i) * 64 + (jt << 4) + colc] = acc[i];
    }
    __syncthreads();
    // O1 ew: r,z ; publish rh (coalesced sc0sc1 store)
    {
      int p0 = (row_l << 6) + (cp << 1);
      float rv0 = sigm(accbuf[p0]);
      float rv1 = sigm(accbuf[p0 + 1]);
      zbuf[p0]     = sigm(accbuf[1024 + p0]);
      zbuf[p0 + 1] = sigm(accbuf[1024 + p0 + 1]);
      stg_cc4(rhg + (row_l << 9) + (s << 6) + (cp << 1),
              pack2(rv0 * h_own[p0], rv1 * h_own[p0 + 1]));
    }
    gb_arrive(ctr); gb_wait(ctr, &ep);             // B1
    // stage rh -> bufA (coalesced 16B coherent loads)
    {
      u32x4 t0 = ldg_cc16(rhg + (tid << 3));
      u32x4 t1 = ldg_cc16(rhg + (tid << 3) + 4096);
      asm volatile("s_waitcnt vmcnt(0)" ::: "memory");
      __builtin_amdgcn_sched_barrier(0);
      int c = tid, row = c >> 6, col = (c << 3) & 511;
      *(u32x4*)((char*)bufA + (row << 10) + (((col << 1)) ^ ((row & 7) << 4))) = t0;
      c = tid + 512; row = c >> 6; col = (c << 3) & 511;
      *(u32x4*)((char*)bufA + (row << 10) + (((col << 1)) ^ ((row & 7) << 4))) = t1;
    }
    __syncthreads();
    // O2 jobs
    {
      int jt = wv & 3, kh = wv >> 2;
      int colg = (s << 6) + (jt << 4) + colc;
      const u16* W = Whh + colg * 512;
      floatx4 acc = (floatx4){0.f,0.f,0.f,0.f};
      #pragma unroll
      for (int kc = kh * 8; kc < kh * 8 + 8; ++kc) {
        int kE = (kc << 5) + (khalf << 3);
        acc = MFMA16(ldA(bufA, 1024, colc, kE), *(const short8*)(W + kE), acc);
      }
      #pragma unroll
      for (int i = 0; i < 4; ++i)
        accbuf[kh * 1024 + (rowc + i) * 64 + (jt << 4) + colc] = acc[i];
    }
    __syncthreads();
    // O2 ew: h' ; publish
    {
      int p0 = (row_l << 6) + (cp << 1);
      float u0 = tanhf(accbuf[p0] + accbuf[1024 + p0]);
      float u1 = tanhf(accbuf[p0 + 1] + accbuf[1024 + p0 + 1]);
      float h0v = h_own[p0], h1v = h_own[p0 + 1];
      float dd = df16[row_l];
      float hn0 = h0v + (1.f - zbuf[p0]) * (u0 - h0v) * dd;
      float hn1 = h1v + (1.f - zbuf[p0 + 1]) * (u1 - h1v) * dd;
      h_own[p0] = hn0; h_own[p0 + 1] = hn1;
      stg_cc4(hg + (row_l << 9) + (s << 6) + (cp << 1), pack2(hn0, hn1));
    }
    gb_arrive(ctr); gb_wait(ctr, &ep);             // B2
    // stage h' -> bufA
    {
      u32x4 t0 = ldg_cc16(hg + (tid << 3));
      u32x4 t1 = ldg_cc16(hg + (tid << 3) + 4096);
      asm volatile("s_waitcnt vmcnt(0)" ::: "memory");
      __builtin_amdgcn_sched_barrier(0);
      int c = tid, row = c >> 6, col = (c << 3) & 511;
      *(u32x4*)((char*)bufA + (row << 10) + (((col << 1)) ^ ((row & 7) << 4))) = t0;
      c = tid + 512; row = c >> 6; col = (c << 3) & 511;
      *(u32x4*)((char*)bufA + (row << 10) + (((col << 1)) ^ ((row & 7) << 4))) = t1;
    }
    __syncthreads();
    // P1
    {
      int colg = (wv << 4) + colc;
      const u16* W = Pw1T + colg * 512;
      floatx4 acc = (floatx4){0.f,0.f,0.f,0.f};
      #pragma unroll
      for (int kc = 0; kc < 16; ++kc) {
        int kE = (kc << 5) + (khalf << 3);
        acc = MFMA16(ldA(bufA, 1024, colc, kE), *(const short8*)(W + kE), acc);
      }
      float bias = p_b1[colg];
      #pragma unroll
      for (int i = 0; i < 4; ++i) {
        int row = rowc + i;
        float v = fmaxf(acc[i] + bias, 0.f);
        *(u16*)((char*)hid1A + ((row << 8) | (((colg << 1)) ^ ((row & 7) << 4)))) = f2bf(v);
      }
    }
    __syncthreads();
    // P2
    if (wv < 4) {
      int colg = (wv << 4) + colc;
      const u16* W = Pw2T + colg * 128;
      floatx4 acc = (floatx4){0.f,0.f,0.f,0.f};
      #pragma unroll
      for (int kc = 0; kc < 4; ++kc) {
        int kE = (kc << 5) + (khalf << 3);
        acc = MFMA16(ldA(hid1A, 256, colc, kE), *(const short8*)(W + kE), acc);
      }
      float bias = p_b2[colg];
      #pragma unroll
      for (int i = 0; i < 4; ++i) pbuf[(rowc + i) * 64 + colg] = acc[i] + bias;
    }
    __syncthreads();
    // L: losses (owned d) + xp publish
    {
      float mean = pbuf[row_l * 64 + d_l];
      float logvar = pbuf[row_l * 64 + 32 + d_l];
      size_t xoff = ((size_t)(b0 + row_l) * T_ + t) * D_ + d_l;
      Xc_s = Xg[xoff];
      Mc_s = Mgl[xoff];
      float mm = mr16[row_l];
      float sg = expf(0.5f * logvar);
      float err = (Xc_s - mean) / sg;
      if (pq == 0) {
        float lv = 0.5f * (err * err + logvar + LOG2PI_f) * Mc_s * mm;
        l1a += lv;
        nlla += lv * invden[t];
      }
      const float* wp = wprep + d_l * 128;
      const float* bp = bprep + d_l * 32;
      float xv[4];
      #pragma unroll
      for (int k = 0; k < 4; ++k) {
        int pi = (pq << 2) + k;
        float v = bp[pi] + Xc_s * wp[pi] + mean * wp[32 + pi] + logvar * wp[64 + pi] + err * wp[96 + pi];
        xv[k] = fmaxf(v, 0.f) * Mc_s;
      }
      u64 packed = (u64)pack2(xv[0], xv[1]) | ((u64)pack2(xv[2], xv[3]) << 32);
      stg_cc8(xpg + (row_l << 10) + (s << 7) + (dloc << 5) + (pq << 2), packed);
    }
    gb_arrive(ctr);                                // B3 arrive
    // G part1: Gwhh partials in regs — hides B3 rendezvous
    floatx4 ar = (floatx4){0.f,0.f,0.f,0.f}, az = ar, an = ar, ah = ar;
    {
      int colg = (s << 6) + (jtG << 4) + colc;
      const u16* bw = Gwhh + colg * 512;
      #pragma unroll
      for (int kc = khG * 8; kc < khG * 8 + 8; ++kc) {
        int kE = (kc << 5) + (khalf << 3);
        short8 a = ldA(bufA, 1024, colc, kE);
        ar = MFMA16(a, *(const short8*)(bw + kE), ar);
        az = MFMA16(a, *(const short8*)(bw + 262144 + kE), az);
        ah = MFMA16(a, *(const short8*)(bw + 524288 + kE), ah);
      }
    }
    gb_wait(ctr, &ep);                             // B3 wait
    // stage xp -> xpL
    {
      u32x4 x0 = ldg_cc16(xpg + (tid << 3));
      u32x4 x1 = ldg_cc16(xpg + (tid << 3) + 4096);
      u32x4 x2 = ldg_cc16(xpg + (tid << 3) + 8192);
      u32x4 x3 = ldg_cc16(xpg + (tid << 3) + 12288);
      asm volatile("s_waitcnt vmcnt(0)" ::: "memory");
      __builtin_amdgcn_sched_barrier(0);
      int c = tid, row = c >> 7, col = (c << 3) & 1023;
      *(u32x4*)((char*)xpL + (row << 11) + (((col << 1)) ^ ((row & 7) << 4))) = x0;
      c = tid + 512; row = c >> 7; col = (c << 3) & 1023;
      *(u32x4*)((char*)xpL + (row << 11) + (((col << 1)) ^ ((row & 7) << 4))) = x1;
      c = tid + 1024; row = c >> 7; col = (c << 3) & 1023;
      *(u32x4*)((char*)xpL + (row << 11) + (((col << 1)) ^ ((row & 7) << 4))) = x2;
      c = tid + 1536; row = c >> 7; col = (c << 3) & 1023;
      *(u32x4*)((char*)xpL + (row << 11) + (((col << 1)) ^ ((row & 7) << 4))) = x3;
    }
    __syncthreads();
    // G part2: Gwih accumulate
    {
      int colg = (s << 6) + (jtG << 4) + colc;
      const u16* bi = Gwih + colg * 1024;
      #pragma unroll
      for (int kc = khG * 16; kc < khG * 16 + 16; ++kc) {
        int kE = (kc << 5) + (khalf << 3);
        short8 a = ldA(xpL, 2048, colc, kE);
        ar = MFMA16(a, *(const short8*)(bi + kE), ar);
        az = MFMA16(a, *(const short8*)(bi + 524288 + kE), az);
        an = MFMA16(a, *(const short8*)(bi + 1048576 + kE), an);
      }
      #pragma unroll
      for (int i = 0; i < 4; ++i) {
        int idx = (rowc + i) * 64 + (jtG << 4) + colc;
        accbuf[(0 + khG) * 1024 + idx] = ar[i];
        accbuf[(2 + khG) * 1024 + idx] = az[i];
        accbuf[(4 + khG) * 1024 + idx] = an[i];
        accbuf[(6 + khG) * 1024 + idx] = ah[i];
      }
    }
    __syncthreads();
    // G ew: gates, h'' ; publish
    {
      int p0 = (row_l << 6) + (cp << 1);
      float hn[2];
      float mm = mr16[row_l];
      #pragma unroll
      for (int q = 0; q < 2; ++q) {
        int p = p0 + q;
        int j = (s << 6) + (cp << 1) + q;
        float Arr = accbuf[p] + accbuf[1024 + p];
        float Azz = accbuf[2048 + p] + accbuf[3072 + p];
        float Ann = accbuf[4096 + p] + accbuf[5120 + p];
        float Ahh = accbuf[6144 + p] + accbuf[7168 + p];
        float rg = sigm(Arr + gru_bih[j] + gru_bhh[j]);
        float zg = sigm(Azz + gru_bih[512 + j] + gru_bhh[512 + j]);
        float ng = tanhf(Ann + gru_bih[1024 + j] + rg * (Ahh + gru_bhh[1024 + j]));
        float h = h_own[p];
        float hv = (1.f - zg) * ng + zg * h;
        hv = (mm > 0.f) ? hv : h;
        h_own[p] = hv;
        hn[q] = hv;
      }
      stg_cc4(hg + (row_l << 9) + (s << 6) + (cp << 1), pack2(hn[0], hn[1]));
    }
    gb_arrive(ctr); gb_wait(ctr, &ep);             // B4
    // stage h'' -> bufA
    {
      u32x4 t0 = ldg_cc16(hg + (tid << 3));
      u32x4 t1 = ldg_cc16(hg + (tid << 3) + 4096);
      asm volatile("s_waitcnt vmcnt(0)" ::: "memory");
      __builtin_amdgcn_sched_barrier(0);
      int c = tid, row = c >> 6, col = (c << 3) & 511;
      *(u32x4*)((char*)bufA + (row << 10) + (((col << 1)) ^ ((row & 7) << 4))) = t0;
      c = tid + 512; row = c >> 6; col = (c << 3) & 511;
      *(u32x4*)((char*)bufA + (row << 10) + (((col << 1)) ^ ((row & 7) << 4))) = t1;
    }
    __syncthreads();
    // P1'
    {
      int colg = (wv << 4) + colc;
      const u16* W = Pw1T + colg * 512;
      floatx4 acc = (floatx4){0.f,0.f,0.f,0.f};
      #pragma unroll
      for (int kc = 0; kc < 16; ++kc) {
        int kE = (kc << 5) + (khalf << 3);
        acc = MFMA16(ldA(bufA, 1024, colc, kE), *(const short8*)(W + kE), acc);
      }
      float bias = p_b1[colg];
      #pragma unroll
      for (int i = 0; i < 4; ++i) {
        int row = rowc + i;
        float v = fmaxf(acc[i] + bias, 0.f);
        *(u16*)((char*)hid1A + ((row << 8) | (((colg << 1)) ^ ((row & 7) << 4)))) = f2bf(v);
      }
    }
    __syncthreads();
    // P2'
    if (wv < 4) {
      int colg = (wv << 4) + colc;
      const u16* W = Pw2T + colg * 128;
      floatx4 acc = (floatx4){0.f,0.f,0.f,0.f};
      #pragma unroll
      for (int kc = 0; kc < 4; ++kc) {
        int kE = (kc << 5) + (khalf << 3);
        acc = MFMA16(ldA(hid1A, 256, colc, kE), *(const short8*)(W + kE), acc);
      }
      float bias = p_b2[colg];
      #pragma unroll
      for (int i = 0; i < 4; ++i) pbuf[(rowc + i) * 64 + colg] = acc[i] + bias;
    }
    __syncthreads();
    // L': kl
    if (pq == 0) {
      float mean2 = pbuf[row_l * 64 + d_l];
      float logvar2 = pbuf[row_l * 64 + 32 + d_l];
      float s2 = expf(logvar2);
      float dm = mean2 - Xc_s;
      float kl = LOGOBS_f - 0.5f * logvar2 + (s2 + dm * dm) * INV2OBS_f - 0.5f;
      l2a += kl * Mc_s * mr16[row_l];
    }
    __syncthreads();
  }

  // final h out (owned slice)
  for (int pos = tid; pos < 1024; pos += 512) {
    int row = pos >> 6, cl = pos & 63;
    out[(size_t)(b0 + row) * H_ + (s << 6) + cl] = h_own[pos];
  }
  // scalar reductions
  #pragma unroll
  for (int off = 32; off > 0; off >>= 1) {
    l1a += __shfl_down(l1a, off, 64);
    l2a += __shfl_down(l2a, off, 64);
    nlla += __shfl_down(nlla, off, 64);
  }
  if (lane == 0) { redbuf[wv] = l1a; redbuf[8 + wv] = l2a; redbuf[16 + wv] = nlla; }
  __syncthreads();
  if (tid == 0) {
    float L1 = 0.f, L2 = 0.f, NL = 0.f;
    for (int w = 0; w < 8; ++w) { L1 += redbuf[w]; L2 += redbuf[8 + w]; NL += redbuf[16 + w]; }
    atomicAdd(out + SCAL_OFF + 0, L1 + 0.1f * L2);
    atomicAdd(out + SCAL_OFF + 1, NL * (1.f / 64.f));
    atomicAdd(out + SCAL_OFF + 2, L1);
    atomicAdd(out + SCAL_OFF + 3, L2);
  }
}

extern "C" void kernel_launch(void* const* d_in, const int* in_sizes, int n_in,
                              void* d_out, int out_size, void* d_ws, size_t ws_size,
                              hipStream_t stream) {
  const float* times  = (const float*)d_in[0];
  const float* X      = (const float*)d_in[1];
  const float* M      = (const float*)d_in[2];
  const float* cov    = (const float*)d_in[3];
  const float* cov_w1 = (const float*)d_in[5];
  const float* cov_b1 = (const float*)d_in[6];
  const float* cov_w2 = (const float*)d_in[7];
  const float* cov_b2 = (const float*)d_in[8];
  const float* p_w1   = (const float*)d_in[9];
  const float* p_b1   = (const float*)d_in[10];
  const float* p_w2   = (const float*)d_in[11];
  const float* p_b2   = (const float*)d_in[12];
  const float* ode_whr = (const float*)d_in[13];
  const float* ode_whz = (const float*)d_in[14];
  const float* ode_whh = (const float*)d_in[15];
  const float* wprep  = (const float*)d_in[16];
  const float* bprep  = (const float*)d_in[17];
  const float* gru_wih = (const float*)d_in[18];
  const float* gru_whh = (const float*)d_in[19];
  const float* gru_bih = (const float*)d_in[20];
  const float* gru_bhh = (const float*)d_in[21];
  const int* num_obs  = (const int*)d_in[22];
  float* out = (float*)d_out;
  u16* ws = (u16*)d_ws;

  hipMemsetAsync(out + SCAL_OFF, 0, 4 * sizeof(float), stream);
  hipMemsetAsync((char*)d_ws + CTR_BYTE, 0, 2048 + 64, stream);
  convw<<<dim3((WS_ELEMS + 255) / 256), dim3(256), 0, stream>>>(
      ode_whr, ode_whz, ode_whh, gru_whh, gru_wih, p_w1, p_w2, ws);

  void* args[] = { (void*)&times, (void*)&X, (void*)&M, (void*)&cov,
                   (void*)&cov_w1, (void*)&cov_b1, (void*)&cov_w2, (void*)&cov_b2,
                   (void*)&p_b1, (void*)&p_b2, (void*)&wprep, (void*)&bprep,
                   (void*)&gru_bih, (void*)&gru_bhh, (void*)&num_obs, (void*)&ws,
                   (void*)&out };
  hipError_t e = hipLaunchCooperativeKernel((const void*)nnfo_main, dim3(256), dim3(512),
                                            args, 0, stream);
  if (e != hipSuccess) {
    // Fallback: plain launch. LDS (97KB) forces 1 WG/CU; grid==CU count -> co-resident.
    nnfo_main<<<dim3(256), dim3(512), 0, stream>>>(
        times, X, M, cov, cov_w1, cov_b1, cov_w2, cov_b2,
        p_b1, p_b2, wprep, bprep, gru_bih, gru_bhh, num_obs, ws, out);
  }
}